// Round 10
// baseline (366.440 us; speedup 1.0000x reference)
//
#include <hip/hip_runtime.h>

#define B_TOT 8192
#define T_LEN 1024
#define HID 10

// Broadcast lane K (0..15) of each row-of-16 to the whole row (VALU DPP, no LDS).
#define BCAST16(v, K)                                                         \
    __int_as_float(__builtin_amdgcn_update_dpp(                               \
        __float_as_int(v), __float_as_int(v), 0x150 | (K), 0xF, 0xF, false))

// Layout: 16 lanes per batch (lanes 0..9 active, one hidden unit each),
// 4 batches/wave, 2048 waves = 2/SIMD balanced -> proven issue-bound regime.
// All math fp32 (f16 ruled out by R9: recurrence amplifies quantization 100x).
// Weights pre-scaled by exp2 args (NL=-log2e for i,f,o; TL=2log2e for g);
// cell state kept scaled C = 2*log2(e)*c.
// Activations: 5 exp2 + 2 rcp via fully-merged rationals:
//   rp3 = rcp((1+ef)(1+ei)(1+eg)):  sig(f) = (1+ei)(1+eg)*rp3,
//                                   sig(i)*tanh(g) = (eg-1)*(1+ef)*rp3
//   rq  = rcp((1+eo)(1+eC)):        sig(o)*tanh(c) = (eC-1)*rq
__global__ __launch_bounds__(256) void lstm_fused_kernel(
    const float* __restrict__ x,      // [B, T]
    const float* __restrict__ W_ih,   // [40, 1]
    const float* __restrict__ W_hh,   // [40, 10]  gate order i,f,g,o
    const float* __restrict__ b_ih,   // [40]
    const float* __restrict__ b_hh,   // [40]
    const float* __restrict__ W_lin,  // [1, 10]
    const float* __restrict__ b_lin,  // [1]
    float* __restrict__ out)          // [B]
{
    const int tid  = threadIdx.x;
    const int j16  = tid & 15;
    const int b    = blockIdx.x * 16 + (tid >> 4);
    const bool act = (j16 < HID);
    const int j    = act ? j16 : 0;          // idle lanes do clamped harmless work

    const float NL = -1.4426950408889634f;   // -log2(e): sigmoid gates i,f,o
    const float TL =  2.8853900817779268f;   // 2*log2(e): tanh gate g / C scale

    // Per-lane pre-scaled weights for unit j (rows q*10+j).
    float w0[HID], w1[HID], w2[HID], w3[HID];
    float wi0, wi1, wi2, wi3, bb0, bb1, bb2, bb3;
    {
        const int r0 = 0*HID+j, r1 = 1*HID+j, r2 = 2*HID+j, r3 = 3*HID+j;
        wi0 = NL*W_ih[r0]; wi1 = NL*W_ih[r1]; wi2 = TL*W_ih[r2]; wi3 = NL*W_ih[r3];
        bb0 = NL*(b_ih[r0]+b_hh[r0]); bb1 = NL*(b_ih[r1]+b_hh[r1]);
        bb2 = TL*(b_ih[r2]+b_hh[r2]); bb3 = NL*(b_ih[r3]+b_hh[r3]);
#pragma unroll
        for (int k = 0; k < HID; ++k) {
            w0[k] = NL*W_hh[r0*HID+k];
            w1[k] = NL*W_hh[r1*HID+k];
            w2[k] = TL*W_hh[r2*HID+k];
            w3[k] = NL*W_hh[r3*HID+k];
        }
    }
    // out = sum_j c_j*W_lin_j + b_lin;  c = C/(2 log2 e) folded into wl.
    const float wl = act ? W_lin[j] * 0.34657359027997264f : 0.0f;

    float h = 0.0f, C = 0.0f;
    const float* xb = x + (size_t)b * T_LEN;

// Two independent 5-FMA chains per gate (a*: k=0..4 after x/bias, s*: k=5..9).
#define LSTM_STEP(xv)                                                         \
    {                                                                         \
        float h0 = BCAST16(h, 0), h1 = BCAST16(h, 1);                         \
        float h2 = BCAST16(h, 2), h3 = BCAST16(h, 3);                         \
        float h4 = BCAST16(h, 4), h5 = BCAST16(h, 5);                         \
        float h6 = BCAST16(h, 6), h7 = BCAST16(h, 7);                         \
        float h8 = BCAST16(h, 8), h9 = BCAST16(h, 9);                         \
        float a0 = fmaf((xv), wi0, bb0);                                      \
        float a1 = fmaf((xv), wi1, bb1);                                      \
        float a2 = fmaf((xv), wi2, bb2);                                      \
        float a3 = fmaf((xv), wi3, bb3);                                      \
        a0 = fmaf(w0[0],h0,a0); a1 = fmaf(w1[0],h0,a1);                       \
        a2 = fmaf(w2[0],h0,a2); a3 = fmaf(w3[0],h0,a3);                       \
        a0 = fmaf(w0[1],h1,a0); a1 = fmaf(w1[1],h1,a1);                       \
        a2 = fmaf(w2[1],h1,a2); a3 = fmaf(w3[1],h1,a3);                       \
        a0 = fmaf(w0[2],h2,a0); a1 = fmaf(w1[2],h2,a1);                       \
        a2 = fmaf(w2[2],h2,a2); a3 = fmaf(w3[2],h2,a3);                       \
        a0 = fmaf(w0[3],h3,a0); a1 = fmaf(w1[3],h3,a1);                       \
        a2 = fmaf(w2[3],h3,a2); a3 = fmaf(w3[3],h3,a3);                       \
        a0 = fmaf(w0[4],h4,a0); a1 = fmaf(w1[4],h4,a1);                       \
        a2 = fmaf(w2[4],h4,a2); a3 = fmaf(w3[4],h4,a3);                       \
        float s0 = w0[5]*h5, s1 = w1[5]*h5, s2 = w2[5]*h5, s3 = w3[5]*h5;     \
        s0 = fmaf(w0[6],h6,s0); s1 = fmaf(w1[6],h6,s1);                       \
        s2 = fmaf(w2[6],h6,s2); s3 = fmaf(w3[6],h6,s3);                       \
        s0 = fmaf(w0[7],h7,s0); s1 = fmaf(w1[7],h7,s1);                       \
        s2 = fmaf(w2[7],h7,s2); s3 = fmaf(w3[7],h7,s3);                       \
        s0 = fmaf(w0[8],h8,s0); s1 = fmaf(w1[8],h8,s1);                       \
        s2 = fmaf(w2[8],h8,s2); s3 = fmaf(w3[8],h8,s3);                       \
        s0 = fmaf(w0[9],h9,s0); s1 = fmaf(w1[9],h9,s1);                       \
        s2 = fmaf(w2[9],h9,s2); s3 = fmaf(w3[9],h9,s3);                       \
        a0 += s0; a1 += s1; a2 += s2; a3 += s3;                               \
        float ei = __builtin_amdgcn_exp2f(a0);                                \
        float ef = __builtin_amdgcn_exp2f(a1);                                \
        float eg = __builtin_amdgcn_exp2f(a2);                                \
        float eo = __builtin_amdgcn_exp2f(a3);                                \
        float pf  = 1.0f + ef;                                                \
        float P   = (1.0f + ei) * (1.0f + eg);                                \
        float rp3 = __builtin_amdgcn_rcpf(P * pf);                            \
        float fg  = P * rp3;                       /* sig(f) */               \
        float igg = TL * (eg - 1.0f) * pf * rp3;   /* 2L*sig(i)*tanh(g) */    \
        C = fminf(fmaf(fg, C, igg), 80.0f);                                   \
        float eC = __builtin_amdgcn_exp2f(C);                                 \
        float rq = __builtin_amdgcn_rcpf((1.0f + eo) * (1.0f + eC));          \
        h = (eC - 1.0f) * rq;                      /* sig(o)*tanh(c) */       \
    }

    float4 xq = *reinterpret_cast<const float4*>(xb);   // steps 0..3
    int t = 0;
    for (; t < T_LEN - 4; t += 4) {
        float4 xn = *reinterpret_cast<const float4*>(xb + t + 4);  // prefetch
        LSTM_STEP(xq.x)
        LSTM_STEP(xq.y)
        LSTM_STEP(xq.z)
        LSTM_STEP(xq.w)
        xq = xn;
    }
    LSTM_STEP(xq.x)
    LSTM_STEP(xq.y)
    LSTM_STEP(xq.z)
    LSTM_STEP(xq.w)
#undef LSTM_STEP

    // out[b] = dot(c, W_lin) + b_lin   (reduce across the 16-lane group, fp32)
    float v = act ? C * wl : 0.0f;
#pragma unroll
    for (int s = 1; s < 16; s <<= 1) v += __shfl_xor(v, s, 16);
    if (j16 == 0) out[b] = v + b_lin[0];
}

extern "C" void kernel_launch(void* const* d_in, const int* in_sizes, int n_in,
                              void* d_out, int out_size, void* d_ws, size_t ws_size,
                              hipStream_t stream) {
    const float* x     = (const float*)d_in[0];
    const float* W_ih  = (const float*)d_in[1];
    const float* W_hh  = (const float*)d_in[2];
    const float* b_ih  = (const float*)d_in[3];
    const float* b_hh  = (const float*)d_in[4];
    const float* W_lin = (const float*)d_in[5];
    const float* b_lin = (const float*)d_in[6];
    float* out = (float*)d_out;

    // 16 batches per 256-thread block -> 512 blocks, 2048 waves (2/SIMD, balanced).
    dim3 grid(B_TOT / 16), block(256);
    hipLaunchKernelGGL(lstm_fused_kernel, grid, block, 0, stream,
                       x, W_ih, W_hh, b_ih, b_hh, W_lin, b_lin, out);
}